// Round 1
// baseline (566.368 us; speedup 1.0000x reference)
//
#include <hip/hip_runtime.h>
#include <hip/hip_bf16.h>
#include <math.h>

// ---- problem constants ----
#define T_TOK  4096      // B*S tokens
#define H_DIM  1024
#define E_NUM  8
#define FF_DIM 4096
#define KSEL   2
#define SLOTS  (T_TOK*KSEL)     // 8192
#define SLOTS_PAD (SLOTS + 128) // tile overrun pad
#define BM 128
#define MAXTILES 72             // 8192/128 + 8

typedef __attribute__((ext_vector_type(8))) short s16x8;
typedef __attribute__((ext_vector_type(4))) float f32x4;

__device__ __forceinline__ unsigned short f2bf(float f){
  unsigned int u = __float_as_uint(f);
  u += 0x7fffu + ((u>>16)&1u);
  return (unsigned short)(u>>16);
}
__device__ __forceinline__ float bf2f(unsigned short h){
  return __uint_as_float(((unsigned int)h)<<16);
}

// ---- workspace layout (all offsets 256-aligned) ----
static constexpr size_t OFF_CNT   = 0;                 // 8 ints
static constexpr size_t OFF_OFFS  = 256;               // 9 ints
static constexpr size_t OFF_NT    = 512;               // 1 int
static constexpr size_t OFF_TILES = 768;               // up to 128 ints
static constexpr size_t OFF_IDX   = 1280;              // [T][2] int
static constexpr size_t OFF_POS   = OFF_IDX  + 32768;  // [T][2] int
static constexpr size_t OFF_WV    = OFF_POS  + 32768;  // [T][2] float
static constexpr size_t OFF_SLOT  = OFF_WV   + 32768;  // [T][2] int
static constexpr size_t OFF_TOK   = OFF_SLOT + 32768;  // [SLOTS] int
static constexpr size_t OFF_WOF   = OFF_TOK  + 32768;  // [SLOTS] float
static constexpr size_t OFF_XG    = OFF_WOF  + 32768;                       // [SLOTS_PAD][H] bf16
static constexpr size_t OFF_W1T   = OFF_XG  + (size_t)SLOTS_PAD*H_DIM*2;    // [E][FF][H] bf16
static constexpr size_t OFF_W2T   = OFF_W1T + (size_t)E_NUM*H_DIM*FF_DIM*2; // [E][H][FF] bf16
static constexpr size_t OFF_MID   = OFF_W2T + (size_t)E_NUM*H_DIM*FF_DIM*2; // [SLOTS_PAD][FF] bf16
static constexpr size_t OFF_Y     = OFF_MID + (size_t)SLOTS_PAD*FF_DIM*2;   // [SLOTS][H] bf16

// ---- gating: logits = x@Wg + bg (fp32), top-2, renormalized weights ----
__global__ __launch_bounds__(64) void gate_kernel(
    const float* __restrict__ x, const float* __restrict__ Wg,
    const float* __restrict__ bg, int* __restrict__ cnt,
    int* __restrict__ idxp, int* __restrict__ posp, float* __restrict__ wvp)
{
  int t = blockIdx.x, lane = threadIdx.x;
  const float* xr = x + (size_t)t*H_DIM;
  float acc[E_NUM];
  #pragma unroll
  for (int e=0;e<E_NUM;e++) acc[e]=0.f;
  for (int i=0;i<H_DIM/64;i++){
    int h = i*64 + lane;
    float xv = xr[h];
    const float* wr_ = Wg + (size_t)h*E_NUM;
    #pragma unroll
    for (int e=0;e<E_NUM;e++) acc[e] += xv*wr_[e];
  }
  #pragma unroll
  for (int e=0;e<E_NUM;e++){
    #pragma unroll
    for (int off=32; off>0; off>>=1) acc[e] += __shfl_xor(acc[e], off);
  }
  if (lane==0){
    float l[E_NUM];
    #pragma unroll
    for (int e=0;e<E_NUM;e++) l[e] = acc[e] + bg[e];
    int i0 = 0;
    #pragma unroll
    for (int e=1;e<E_NUM;e++) if (l[e] > l[i0]) i0 = e;
    int i1 = (i0==0)?1:0;
    #pragma unroll
    for (int e=0;e<E_NUM;e++) if (e!=i0 && l[e] > l[i1]) i1 = e;
    // top-2 softmax renormalized: w0 = 1/(1+exp(l1-l0))
    float p1 = expf(l[i1]-l[i0]);
    float s  = 1.f + p1;
    float w0 = 1.f/s, w1 = p1/s;
    int pos0 = atomicAdd(&cnt[i0],1);
    int pos1 = atomicAdd(&cnt[i1],1);
    idxp[t*2]=i0; idxp[t*2+1]=i1;
    posp[t*2]=pos0; posp[t*2+1]=pos1;
    wvp[t*2]=w0; wvp[t*2+1]=w1;
  }
}

// ---- plan: prefix sums + tile worklist ----
__global__ void plan_kernel(const int* __restrict__ cnt, int* __restrict__ offs,
                            int* __restrict__ tiles, int* __restrict__ ntiles)
{
  int o=0, n=0;
  for (int e=0;e<E_NUM;e++){
    offs[e]=o;
    int c=cnt[e];
    int nt=(c+BM-1)/BM;
    for (int m=0;m<nt;m++) tiles[n++] = (e<<16)|m;
    o+=c;
  }
  offs[E_NUM]=o;
  *ntiles=n;
}

// ---- scatter: token -> slot mapping ----
__global__ void scatter_kernel(const int* __restrict__ idxp, const int* __restrict__ posp,
                               const float* __restrict__ wvp, const int* __restrict__ offs,
                               int* __restrict__ tok_of, float* __restrict__ w_of,
                               int* __restrict__ slot_of)
{
  int i = blockIdx.x*blockDim.x + threadIdx.x;
  if (i >= SLOTS) return;
  int t = i>>1, k = i&1;
  int e = idxp[t*2+k];
  int slot = offs[e] + posp[t*2+k];
  tok_of[slot] = t;
  w_of[slot]   = wvp[t*2+k];
  slot_of[t*2+k] = slot;
}

// ---- gather x rows into per-expert-contiguous bf16 ----
__global__ __launch_bounds__(256) void gather_kernel(
    const float* __restrict__ x, const int* __restrict__ tok_of,
    unsigned short* __restrict__ Xg)
{
  int slot = blockIdx.x;
  int t = tok_of[slot];
  const float4* src = (const float4*)(x + (size_t)t*H_DIM);
  float4 v = src[threadIdx.x];
  ushort4 o;
  o.x=f2bf(v.x); o.y=f2bf(v.y); o.z=f2bf(v.z); o.w=f2bf(v.w);
  ((ushort4*)(Xg + (size_t)slot*H_DIM))[threadIdx.x] = o;
}

// ---- transpose + convert: in [e][R][C] fp32 -> out [e][C][R] bf16 ----
__global__ __launch_bounds__(256) void transconv_kernel(
    const float* __restrict__ in, unsigned short* __restrict__ out, int R, int C)
{
  __shared__ float tile[32][33];
  int e = blockIdx.z;
  const float* inp = in + (size_t)e*R*C;
  unsigned short* op = out + (size_t)e*R*C;
  int c0 = blockIdx.x*32, r0 = blockIdx.y*32;
  for (int i=threadIdx.y; i<32; i+=8)
    tile[i][threadIdx.x] = inp[(size_t)(r0+i)*C + c0 + threadIdx.x];
  __syncthreads();
  for (int i=threadIdx.y; i<32; i+=8)
    op[(size_t)(c0+i)*R + r0 + threadIdx.x] = f2bf(tile[threadIdx.x][i]);
}

// ---- grouped GEMM: Out[row][N] = epi(A[row][K] @ Bt[e][N][K]^T + bias[e][N]) ----
// MODE 0: gelu epilogue (GEMM1). MODE 1: scale-by-gate-weight epilogue (GEMM2).
template<int MODE>
__global__ __launch_bounds__(256) void gemm_kernel(
    const unsigned short* __restrict__ A,
    const unsigned short* __restrict__ Bt,
    const float* __restrict__ bias,
    unsigned short* __restrict__ Out,
    const int* __restrict__ tiles, const int* __restrict__ ntiles,
    const int* __restrict__ cnt, const int* __restrict__ offs,
    const float* __restrict__ w_of,
    int N, int K)
{
  int tidx = blockIdx.x;
  if (tidx >= *ntiles) return;
  int packed = tiles[tidx];
  int e = packed>>16, mt = packed & 0xffff;
  int row0 = offs[e] + mt*BM;
  int nvalid = cnt[e] - mt*BM; if (nvalid > BM) nvalid = BM;
  int col0 = blockIdx.y*128;
  const unsigned short* Be = Bt + (size_t)e*N*K;

  __shared__ unsigned short As[128][40];  // +8 bf16 pad: 2-way bank aliasing only
  __shared__ unsigned short Bs[128][40];

  int t = threadIdx.x;
  int wid = t>>6, lane = t&63;
  int wr = (wid>>1)*64, wc = (wid&1)*64;
  int fr = lane&15, fq = lane>>4;

  f32x4 acc[4][4];
  #pragma unroll
  for (int i=0;i<4;i++)
    #pragma unroll
    for (int j=0;j<4;j++) acc[i][j] = (f32x4){0.f,0.f,0.f,0.f};

  for (int k0=0; k0<K; k0+=32){
    #pragma unroll
    for (int i=0;i<2;i++){
      int c = t + i*256;          // 0..511
      int r = c>>2, q = c&3;      // 128 rows x 4 chunks of 8 bf16
      *(s16x8*)&As[r][q*8] = *(const s16x8*)(A  + (size_t)(row0+r)*K + k0 + q*8);
      *(s16x8*)&Bs[r][q*8] = *(const s16x8*)(Be + (size_t)(col0+r)*K + k0 + q*8);
    }
    __syncthreads();
    s16x8 af[4], bfr[4];
    #pragma unroll
    for (int i=0;i<4;i++){
      af[i]  = *(const s16x8*)&As[wr + i*16 + fr][fq*8];
      bfr[i] = *(const s16x8*)&Bs[wc + i*16 + fr][fq*8];
    }
    #pragma unroll
    for (int i=0;i<4;i++)
      #pragma unroll
      for (int j=0;j<4;j++)
        acc[i][j] = __builtin_amdgcn_mfma_f32_16x16x32_bf16(af[i], bfr[j], acc[i][j], 0,0,0);
    __syncthreads();
  }

  // epilogue: C/D layout col=lane&15, row=(lane>>4)*4+reg (m89-verified)
  #pragma unroll
  for (int i=0;i<4;i++){
    #pragma unroll
    for (int r=0;r<4;r++){
      int lrow = wr + i*16 + fq*4 + r;
      if (lrow < nvalid){
        int grow = row0 + lrow;
        float scale = (MODE==1) ? w_of[grow] : 0.f;
        #pragma unroll
        for (int j=0;j<4;j++){
          int col = col0 + wc + j*16 + fr;
          float v = acc[i][j][r] + bias[(size_t)e*N + col];
          if (MODE==0) v = 0.5f*v*(1.f + erff(v*0.70710678118654752f));  // exact gelu
          else         v *= scale;
          Out[(size_t)grow*N + col] = f2bf(v);
        }
      }
    }
  }
}

// ---- combine: out[t] = y[slot0] + y[slot1] (gate weights already applied) ----
__global__ __launch_bounds__(256) void combine_kernel(
    const unsigned short* __restrict__ y, const int* __restrict__ slot_of,
    float* __restrict__ out)
{
  int tok = blockIdx.x;
  int s0 = slot_of[tok*2], s1 = slot_of[tok*2+1];
  const ushort4* y0 = (const ushort4*)(y + (size_t)s0*H_DIM);
  const ushort4* y1 = (const ushort4*)(y + (size_t)s1*H_DIM);
  float4* o = (float4*)(out + (size_t)tok*H_DIM);
  ushort4 a = y0[threadIdx.x], b = y1[threadIdx.x];
  float4 r;
  r.x = bf2f(a.x)+bf2f(b.x);
  r.y = bf2f(a.y)+bf2f(b.y);
  r.z = bf2f(a.z)+bf2f(b.z);
  r.w = bf2f(a.w)+bf2f(b.w);
  o[threadIdx.x] = r;
}

extern "C" void kernel_launch(void* const* d_in, const int* in_sizes, int n_in,
                              void* d_out, int out_size, void* d_ws, size_t ws_size,
                              hipStream_t stream) {
  const float* x  = (const float*)d_in[0];
  const float* Wg = (const float*)d_in[1];
  const float* bg = (const float*)d_in[2];
  const float* W1 = (const float*)d_in[3];
  const float* b1 = (const float*)d_in[4];
  const float* W2 = (const float*)d_in[5];
  const float* b2 = (const float*)d_in[6];
  float* out = (float*)d_out;
  char* ws = (char*)d_ws;

  int*   cnt     = (int*)  (ws + OFF_CNT);
  int*   offs    = (int*)  (ws + OFF_OFFS);
  int*   ntiles  = (int*)  (ws + OFF_NT);
  int*   tiles   = (int*)  (ws + OFF_TILES);
  int*   idxp    = (int*)  (ws + OFF_IDX);
  int*   posp    = (int*)  (ws + OFF_POS);
  float* wvp     = (float*)(ws + OFF_WV);
  int*   slot_of = (int*)  (ws + OFF_SLOT);
  int*   tok_of  = (int*)  (ws + OFF_TOK);
  float* w_of    = (float*)(ws + OFF_WOF);
  unsigned short* Xg  = (unsigned short*)(ws + OFF_XG);
  unsigned short* W1t = (unsigned short*)(ws + OFF_W1T);
  unsigned short* W2t = (unsigned short*)(ws + OFF_W2T);
  unsigned short* mid = (unsigned short*)(ws + OFF_MID);
  unsigned short* y   = (unsigned short*)(ws + OFF_Y);

  hipMemsetAsync(ws + OFF_CNT, 0, 32, stream);

  gate_kernel<<<T_TOK, 64, 0, stream>>>(x, Wg, bg, cnt, idxp, posp, wvp);
  plan_kernel<<<1, 1, 0, stream>>>(cnt, offs, tiles, ntiles);
  scatter_kernel<<<SLOTS/256, 256, 0, stream>>>(idxp, posp, wvp, offs, tok_of, w_of, slot_of);
  gather_kernel<<<SLOTS, 256, 0, stream>>>(x, tok_of, Xg);

  // W1 [E][H][FF] -> W1t [E][FF][H] ; W2 [E][FF][H] -> W2t [E][H][FF]
  transconv_kernel<<<dim3(FF_DIM/32, H_DIM/32, E_NUM), dim3(32,8), 0, stream>>>(W1, W1t, H_DIM, FF_DIM);
  transconv_kernel<<<dim3(H_DIM/32, FF_DIM/32, E_NUM), dim3(32,8), 0, stream>>>(W2, W2t, FF_DIM, H_DIM);

  // GEMM1: mid = gelu(Xg @ W1[e] + b1[e]), N=FF, K=H
  gemm_kernel<0><<<dim3(MAXTILES, FF_DIM/128), 256, 0, stream>>>(
      Xg, W1t, b1, mid, tiles, ntiles, cnt, offs, nullptr, FF_DIM, H_DIM);
  // GEMM2: y = (mid @ W2[e] + b2[e]) * gate_w, N=H, K=FF
  gemm_kernel<1><<<dim3(MAXTILES, H_DIM/128), 256, 0, stream>>>(
      mid, W2t, b2, y, tiles, ntiles, cnt, offs, w_of, H_DIM, FF_DIM);

  combine_kernel<<<T_TOK, 256, 0, stream>>>(y, slot_of, out);
}

// Round 2
// 516.793 us; speedup vs baseline: 1.0959x; 1.0959x over previous
//
#include <hip/hip_runtime.h>
#include <hip/hip_bf16.h>
#include <math.h>

// ---- problem constants ----
#define T_TOK  4096      // B*S tokens
#define H_DIM  1024
#define E_NUM  8
#define FF_DIM 4096
#define KSEL   2
#define SLOTS  (T_TOK*KSEL)     // 8192
#define SLOTS_PAD (SLOTS + 128) // tile overrun pad
#define BM 128
#define MAXTILES 72             // 8192/128 + 8

typedef __attribute__((ext_vector_type(8))) short s16x8;
typedef __attribute__((ext_vector_type(4))) float f32x4;

typedef __attribute__((address_space(1))) const void global_cvoid;
typedef __attribute__((address_space(3))) void lds_void;

__device__ __forceinline__ unsigned short f2bf(float f){
  unsigned int u = __float_as_uint(f);
  u += 0x7fffu + ((u>>16)&1u);
  return (unsigned short)(u>>16);
}
__device__ __forceinline__ float bf2f(unsigned short h){
  return __uint_as_float(((unsigned int)h)<<16);
}

// ---- workspace layout (all offsets 256-aligned) ----
static constexpr size_t OFF_CNT   = 0;                 // 8 ints
static constexpr size_t OFF_OFFS  = 256;               // 9 ints
static constexpr size_t OFF_NT    = 512;               // 1 int
static constexpr size_t OFF_TILES = 768;               // up to 128 ints
static constexpr size_t OFF_IDX   = 1280;              // [T][2] int
static constexpr size_t OFF_POS   = OFF_IDX  + 32768;  // [T][2] int
static constexpr size_t OFF_WV    = OFF_POS  + 32768;  // [T][2] float
static constexpr size_t OFF_SLOT  = OFF_WV   + 32768;  // [T][2] int
static constexpr size_t OFF_TOK   = OFF_SLOT + 32768;  // [SLOTS] int
static constexpr size_t OFF_WOF   = OFF_TOK  + 32768;  // [SLOTS] float
static constexpr size_t OFF_XG    = OFF_WOF  + 32768;                       // [SLOTS_PAD][H] bf16
static constexpr size_t OFF_W1T   = OFF_XG  + (size_t)SLOTS_PAD*H_DIM*2;    // [E][FF][H] bf16
static constexpr size_t OFF_W2T   = OFF_W1T + (size_t)E_NUM*H_DIM*FF_DIM*2; // [E][H][FF] bf16
static constexpr size_t OFF_MID   = OFF_W2T + (size_t)E_NUM*H_DIM*FF_DIM*2; // [SLOTS_PAD][FF] bf16
static constexpr size_t OFF_Y     = OFF_MID + (size_t)SLOTS_PAD*FF_DIM*2;   // [SLOTS][H] bf16

// ---- gating: logits = x@Wg + bg (fp32), top-2, renormalized weights ----
__global__ __launch_bounds__(64) void gate_kernel(
    const float* __restrict__ x, const float* __restrict__ Wg,
    const float* __restrict__ bg, int* __restrict__ cnt,
    int* __restrict__ idxp, int* __restrict__ posp, float* __restrict__ wvp)
{
  int t = blockIdx.x, lane = threadIdx.x;
  const float* xr = x + (size_t)t*H_DIM;
  float acc[E_NUM];
  #pragma unroll
  for (int e=0;e<E_NUM;e++) acc[e]=0.f;
  for (int i=0;i<H_DIM/64;i++){
    int h = i*64 + lane;
    float xv = xr[h];
    const float* wr_ = Wg + (size_t)h*E_NUM;
    #pragma unroll
    for (int e=0;e<E_NUM;e++) acc[e] += xv*wr_[e];
  }
  #pragma unroll
  for (int e=0;e<E_NUM;e++){
    #pragma unroll
    for (int off=32; off>0; off>>=1) acc[e] += __shfl_xor(acc[e], off);
  }
  if (lane==0){
    float l[E_NUM];
    #pragma unroll
    for (int e=0;e<E_NUM;e++) l[e] = acc[e] + bg[e];
    int i0 = 0;
    #pragma unroll
    for (int e=1;e<E_NUM;e++) if (l[e] > l[i0]) i0 = e;
    int i1 = (i0==0)?1:0;
    #pragma unroll
    for (int e=0;e<E_NUM;e++) if (e!=i0 && l[e] > l[i1]) i1 = e;
    // top-2 softmax renormalized: w0 = 1/(1+exp(l1-l0))
    float p1 = expf(l[i1]-l[i0]);
    float s  = 1.f + p1;
    float w0 = 1.f/s, w1 = p1/s;
    int pos0 = atomicAdd(&cnt[i0],1);
    int pos1 = atomicAdd(&cnt[i1],1);
    idxp[t*2]=i0; idxp[t*2+1]=i1;
    posp[t*2]=pos0; posp[t*2+1]=pos1;
    wvp[t*2]=w0; wvp[t*2+1]=w1;
  }
}

// ---- plan: prefix sums + tile worklist ----
__global__ void plan_kernel(const int* __restrict__ cnt, int* __restrict__ offs,
                            int* __restrict__ tiles, int* __restrict__ ntiles)
{
  int o=0, n=0;
  for (int e=0;e<E_NUM;e++){
    offs[e]=o;
    int c=cnt[e];
    int nt=(c+BM-1)/BM;
    for (int m=0;m<nt;m++) tiles[n++] = (e<<16)|m;
    o+=c;
  }
  offs[E_NUM]=o;
  *ntiles=n;
}

// ---- scatter: token -> slot mapping ----
__global__ void scatter_kernel(const int* __restrict__ idxp, const int* __restrict__ posp,
                               const float* __restrict__ wvp, const int* __restrict__ offs,
                               int* __restrict__ tok_of, float* __restrict__ w_of,
                               int* __restrict__ slot_of)
{
  int i = blockIdx.x*blockDim.x + threadIdx.x;
  if (i >= SLOTS) return;
  int t = i>>1, k = i&1;
  int e = idxp[t*2+k];
  int slot = offs[e] + posp[t*2+k];
  tok_of[slot] = t;
  w_of[slot]   = wvp[t*2+k];
  slot_of[t*2+k] = slot;
}

// ---- gather x rows into per-expert-contiguous bf16 ----
__global__ __launch_bounds__(256) void gather_kernel(
    const float* __restrict__ x, const int* __restrict__ tok_of,
    unsigned short* __restrict__ Xg)
{
  int slot = blockIdx.x;
  int t = tok_of[slot];
  const float4* src = (const float4*)(x + (size_t)t*H_DIM);
  float4 v = src[threadIdx.x];
  ushort4 o;
  o.x=f2bf(v.x); o.y=f2bf(v.y); o.z=f2bf(v.z); o.w=f2bf(v.w);
  ((ushort4*)(Xg + (size_t)slot*H_DIM))[threadIdx.x] = o;
}

// ---- transpose + convert: in [e][R][C] fp32 -> out [e][C][R] bf16 ----
// 64x64 tile, float4 reads, ushort4 transposed writes.
__global__ __launch_bounds__(256) void transconv_kernel(
    const float* __restrict__ in, unsigned short* __restrict__ out, int R, int C)
{
  __shared__ float tile[64][65];
  int e = blockIdx.z;
  const float* inp = in + (size_t)e*R*C;
  unsigned short* op = out + (size_t)e*R*C;
  int c0 = blockIdx.x*64, r0 = blockIdx.y*64;
  int tx = threadIdx.x & 15, ty = threadIdx.x >> 4;   // 16x16
  #pragma unroll
  for (int i=0;i<4;i++){
    int r = i*16 + ty;
    float4 v = *(const float4*)(inp + (size_t)(r0+r)*C + c0 + tx*4);
    tile[r][tx*4+0]=v.x; tile[r][tx*4+1]=v.y; tile[r][tx*4+2]=v.z; tile[r][tx*4+3]=v.w;
  }
  __syncthreads();
  #pragma unroll
  for (int i=0;i<4;i++){
    int c = i*16 + ty;
    ushort4 o;
    o.x = f2bf(tile[tx*4+0][c]);
    o.y = f2bf(tile[tx*4+1][c]);
    o.z = f2bf(tile[tx*4+2][c]);
    o.w = f2bf(tile[tx*4+3][c]);
    *(ushort4*)(op + (size_t)(c0+c)*R + r0 + tx*4) = o;
  }
}

// ---- grouped GEMM, m97 structure ----
// Out[row][N] = epi(A[row][K] @ Bt[e][N][K]^T + bias[e][N])
// MODE 0: gelu epilogue (GEMM1). MODE 1: scale-by-gate-weight epilogue (GEMM2).
// Staging: global_load_lds width-16 into linear (unpadded) LDS tiles.
template<int MODE>
__global__ __launch_bounds__(256) void gemm_kernel(
    const unsigned short* __restrict__ A,
    const unsigned short* __restrict__ Bt,
    const float* __restrict__ bias,
    unsigned short* __restrict__ Out,
    const int* __restrict__ tiles, const int* __restrict__ ntiles,
    const int* __restrict__ cnt, const int* __restrict__ offs,
    const float* __restrict__ w_of,
    int N, int K)
{
  int tidx = blockIdx.x;
  if (tidx >= *ntiles) return;
  int packed = tiles[tidx];
  int e = packed>>16, mt = packed & 0xffff;
  int row0 = offs[e] + mt*BM;
  int nvalid = cnt[e] - mt*BM; if (nvalid > BM) nvalid = BM;
  int col0 = blockIdx.y*128;
  const unsigned short* Be = Bt + (size_t)e*N*K;

  // linear LDS: [128 rows][32 k] bf16, 64 B/row. global_load_lds needs no pad.
  __shared__ unsigned short As[128*32];
  __shared__ unsigned short Bs[128*32];

  int t = threadIdx.x;
  int wid = t>>6, lane = t&63;
  int wr = (wid>>1)*64, wc = (wid&1)*64;
  int fr = lane&15, fq = lane>>4;
  int cb = wid*64;                 // wave-uniform chunk base (16B chunks)

  f32x4 acc[4][4];
  #pragma unroll
  for (int i=0;i<4;i++)
    #pragma unroll
    for (int j=0;j<4;j++) acc[i][j] = (f32x4){0.f,0.f,0.f,0.f};

  for (int k0=0; k0<K; k0+=32){
    // stage A-tile (8 KB) + B-tile (8 KB): 4 global_load_lds_dwordx4 per wave.
    // chunk c (16 B) -> LDS byte c*16; row = c>>2, kq = c&3 (8 bf16 per chunk).
    #pragma unroll
    for (int i=0;i<2;i++){
      int c = cb + i*256 + lane;
      int r = c>>2, q = c&3;
      __builtin_amdgcn_global_load_lds(
        (global_cvoid*)(A  + (size_t)(row0+r)*K + k0 + q*8),
        (lds_void*)((char*)As + (size_t)(cb + i*256)*16), 16, 0, 0);
      __builtin_amdgcn_global_load_lds(
        (global_cvoid*)(Be + (size_t)(col0+r)*K + k0 + q*8),
        (lds_void*)((char*)Bs + (size_t)(cb + i*256)*16), 16, 0, 0);
    }
    __syncthreads();
    s16x8 af[4], bfr[4];
    #pragma unroll
    for (int i=0;i<4;i++){
      af[i]  = *(const s16x8*)&As[(wr + i*16 + fr)*32 + fq*8];
      bfr[i] = *(const s16x8*)&Bs[(wc + i*16 + fr)*32 + fq*8];
    }
    #pragma unroll
    for (int i=0;i<4;i++)
      #pragma unroll
      for (int j=0;j<4;j++)
        acc[i][j] = __builtin_amdgcn_mfma_f32_16x16x32_bf16(af[i], bfr[j], acc[i][j], 0,0,0);
    __syncthreads();
  }

  // epilogue: C/D layout col=lane&15, row=(lane>>4)*4+reg (m89-verified)
  #pragma unroll
  for (int i=0;i<4;i++){
    #pragma unroll
    for (int r=0;r<4;r++){
      int lrow = wr + i*16 + fq*4 + r;
      if (lrow < nvalid){
        int grow = row0 + lrow;
        float scale = (MODE==1) ? w_of[grow] : 0.f;
        #pragma unroll
        for (int j=0;j<4;j++){
          int col = col0 + wc + j*16 + fr;
          float v = acc[i][j][r] + bias[(size_t)e*N + col];
          if (MODE==0) v = 0.5f*v*(1.f + erff(v*0.70710678118654752f));  // exact gelu
          else         v *= scale;
          Out[(size_t)grow*N + col] = f2bf(v);
        }
      }
    }
  }
}

// ---- combine: out[t] = y[slot0] + y[slot1] (gate weights already applied) ----
__global__ __launch_bounds__(256) void combine_kernel(
    const unsigned short* __restrict__ y, const int* __restrict__ slot_of,
    float* __restrict__ out)
{
  int tok = blockIdx.x;
  int s0 = slot_of[tok*2], s1 = slot_of[tok*2+1];
  const ushort4* y0 = (const ushort4*)(y + (size_t)s0*H_DIM);
  const ushort4* y1 = (const ushort4*)(y + (size_t)s1*H_DIM);
  float4* o = (float4*)(out + (size_t)tok*H_DIM);
  ushort4 a = y0[threadIdx.x], b = y1[threadIdx.x];
  float4 r;
  r.x = bf2f(a.x)+bf2f(b.x);
  r.y = bf2f(a.y)+bf2f(b.y);
  r.z = bf2f(a.z)+bf2f(b.z);
  r.w = bf2f(a.w)+bf2f(b.w);
  o[threadIdx.x] = r;
}

extern "C" void kernel_launch(void* const* d_in, const int* in_sizes, int n_in,
                              void* d_out, int out_size, void* d_ws, size_t ws_size,
                              hipStream_t stream) {
  const float* x  = (const float*)d_in[0];
  const float* Wg = (const float*)d_in[1];
  const float* bg = (const float*)d_in[2];
  const float* W1 = (const float*)d_in[3];
  const float* b1 = (const float*)d_in[4];
  const float* W2 = (const float*)d_in[5];
  const float* b2 = (const float*)d_in[6];
  float* out = (float*)d_out;
  char* ws = (char*)d_ws;

  int*   cnt     = (int*)  (ws + OFF_CNT);
  int*   offs    = (int*)  (ws + OFF_OFFS);
  int*   ntiles  = (int*)  (ws + OFF_NT);
  int*   tiles   = (int*)  (ws + OFF_TILES);
  int*   idxp    = (int*)  (ws + OFF_IDX);
  int*   posp    = (int*)  (ws + OFF_POS);
  float* wvp     = (float*)(ws + OFF_WV);
  int*   slot_of = (int*)  (ws + OFF_SLOT);
  int*   tok_of  = (int*)  (ws + OFF_TOK);
  float* w_of    = (float*)(ws + OFF_WOF);
  unsigned short* Xg  = (unsigned short*)(ws + OFF_XG);
  unsigned short* W1t = (unsigned short*)(ws + OFF_W1T);
  unsigned short* W2t = (unsigned short*)(ws + OFF_W2T);
  unsigned short* mid = (unsigned short*)(ws + OFF_MID);
  unsigned short* y   = (unsigned short*)(ws + OFF_Y);

  hipMemsetAsync(ws + OFF_CNT, 0, 32, stream);

  gate_kernel<<<T_TOK, 64, 0, stream>>>(x, Wg, bg, cnt, idxp, posp, wvp);
  plan_kernel<<<1, 1, 0, stream>>>(cnt, offs, tiles, ntiles);
  scatter_kernel<<<SLOTS/256, 256, 0, stream>>>(idxp, posp, wvp, offs, tok_of, w_of, slot_of);
  gather_kernel<<<SLOTS, 256, 0, stream>>>(x, tok_of, Xg);

  // W1 [E][H][FF] -> W1t [E][FF][H] ; W2 [E][FF][H] -> W2t [E][H][FF]
  transconv_kernel<<<dim3(FF_DIM/64, H_DIM/64, E_NUM), 256, 0, stream>>>(W1, W1t, H_DIM, FF_DIM);
  transconv_kernel<<<dim3(H_DIM/64, FF_DIM/64, E_NUM), 256, 0, stream>>>(W2, W2t, FF_DIM, H_DIM);

  // GEMM1: mid = gelu(Xg @ W1[e] + b1[e]), N=FF, K=H
  gemm_kernel<0><<<dim3(MAXTILES, FF_DIM/128), 256, 0, stream>>>(
      Xg, W1t, b1, mid, tiles, ntiles, cnt, offs, nullptr, FF_DIM, H_DIM);
  // GEMM2: y = (mid @ W2[e] + b2[e]) * gate_w, N=H, K=FF
  gemm_kernel<1><<<dim3(MAXTILES, H_DIM/128), 256, 0, stream>>>(
      mid, W2t, b2, y, tiles, ntiles, cnt, offs, w_of, H_DIM, FF_DIM);

  combine_kernel<<<T_TOK, 256, 0, stream>>>(y, slot_of, out);
}

// Round 3
// 470.945 us; speedup vs baseline: 1.2026x; 1.0974x over previous
//
#include <hip/hip_runtime.h>
#include <hip/hip_bf16.h>
#include <math.h>

// ---- problem constants ----
#define T_TOK  4096      // B*S tokens
#define H_DIM  1024
#define E_NUM  8
#define FF_DIM 4096
#define KSEL   2
#define SLOTS  (T_TOK*KSEL)     // 8192
#define SLOTS_PAD (SLOTS + 128) // tile overrun pad
#define BM 128
#define MAXTILES 72             // 8192/128 + 8

typedef __attribute__((ext_vector_type(8))) short s16x8;
typedef __attribute__((ext_vector_type(8))) unsigned short u16x8;
typedef __attribute__((ext_vector_type(4))) float f32x4;

typedef __attribute__((address_space(1))) const void global_cvoid;
typedef __attribute__((address_space(3))) void lds_void;

__device__ __forceinline__ unsigned short f2bf(float f){
  unsigned int u = __float_as_uint(f);
  u += 0x7fffu + ((u>>16)&1u);
  return (unsigned short)(u>>16);
}
__device__ __forceinline__ float bf2f(unsigned short h){
  return __uint_as_float(((unsigned int)h)<<16);
}

// ---- workspace layout (all offsets 256-aligned) ----
static constexpr size_t OFF_CNT   = 0;                 // 8 ints
static constexpr size_t OFF_OFFS  = 256;               // 9 ints
static constexpr size_t OFF_NT    = 512;               // 1 int
static constexpr size_t OFF_TILES = 768;               // up to 128 ints
static constexpr size_t OFF_IDX   = 1280;              // [T][2] int
static constexpr size_t OFF_POS   = OFF_IDX  + 32768;  // [T][2] int
static constexpr size_t OFF_WV    = OFF_POS  + 32768;  // [T][2] float
static constexpr size_t OFF_SLOT  = OFF_WV   + 32768;  // [T][2] int
static constexpr size_t OFF_TOK   = OFF_SLOT + 32768;  // [SLOTS] int
static constexpr size_t OFF_WOF   = OFF_TOK  + 32768;  // [SLOTS] float
static constexpr size_t OFF_XG    = OFF_WOF  + 32768;                       // [SLOTS_PAD][H] bf16
static constexpr size_t OFF_W1T   = OFF_XG  + (size_t)SLOTS_PAD*H_DIM*2;    // [E][FF][H] bf16
static constexpr size_t OFF_W2T   = OFF_W1T + (size_t)E_NUM*H_DIM*FF_DIM*2; // [E][H][FF] bf16
static constexpr size_t OFF_MID   = OFF_W2T + (size_t)E_NUM*H_DIM*FF_DIM*2; // [SLOTS_PAD][FF] bf16
static constexpr size_t OFF_Y     = OFF_MID + (size_t)SLOTS_PAD*FF_DIM*2;   // [SLOTS][H] bf16

// ---- gating: logits = x@Wg + bg (fp32), top-2, renormalized weights ----
__global__ __launch_bounds__(64) void gate_kernel(
    const float* __restrict__ x, const float* __restrict__ Wg,
    const float* __restrict__ bg, int* __restrict__ cnt,
    int* __restrict__ idxp, int* __restrict__ posp, float* __restrict__ wvp)
{
  int t = blockIdx.x, lane = threadIdx.x;
  const float* xr = x + (size_t)t*H_DIM;
  float acc[E_NUM];
  #pragma unroll
  for (int e=0;e<E_NUM;e++) acc[e]=0.f;
  for (int i=0;i<H_DIM/64;i++){
    int h = i*64 + lane;
    float xv = xr[h];
    const float* wr_ = Wg + (size_t)h*E_NUM;
    #pragma unroll
    for (int e=0;e<E_NUM;e++) acc[e] += xv*wr_[e];
  }
  #pragma unroll
  for (int e=0;e<E_NUM;e++){
    #pragma unroll
    for (int off=32; off>0; off>>=1) acc[e] += __shfl_xor(acc[e], off);
  }
  if (lane==0){
    float l[E_NUM];
    #pragma unroll
    for (int e=0;e<E_NUM;e++) l[e] = acc[e] + bg[e];
    int i0 = 0;
    #pragma unroll
    for (int e=1;e<E_NUM;e++) if (l[e] > l[i0]) i0 = e;
    int i1 = (i0==0)?1:0;
    #pragma unroll
    for (int e=0;e<E_NUM;e++) if (e!=i0 && l[e] > l[i1]) i1 = e;
    // top-2 softmax renormalized: w0 = 1/(1+exp(l1-l0))
    float p1 = expf(l[i1]-l[i0]);
    float s  = 1.f + p1;
    float w0 = 1.f/s, w1 = p1/s;
    int pos0 = atomicAdd(&cnt[i0],1);
    int pos1 = atomicAdd(&cnt[i1],1);
    idxp[t*2]=i0; idxp[t*2+1]=i1;
    posp[t*2]=pos0; posp[t*2+1]=pos1;
    wvp[t*2]=w0; wvp[t*2+1]=w1;
  }
}

// ---- plan: prefix sums + tile worklist ----
__global__ void plan_kernel(const int* __restrict__ cnt, int* __restrict__ offs,
                            int* __restrict__ tiles, int* __restrict__ ntiles)
{
  int o=0, n=0;
  for (int e=0;e<E_NUM;e++){
    offs[e]=o;
    int c=cnt[e];
    int nt=(c+BM-1)/BM;
    for (int m=0;m<nt;m++) tiles[n++] = (e<<16)|m;
    o+=c;
  }
  offs[E_NUM]=o;
  *ntiles=n;
}

// ---- scatter: token -> slot mapping ----
__global__ void scatter_kernel(const int* __restrict__ idxp, const int* __restrict__ posp,
                               const float* __restrict__ wvp, const int* __restrict__ offs,
                               int* __restrict__ tok_of, float* __restrict__ w_of,
                               int* __restrict__ slot_of)
{
  int i = blockIdx.x*blockDim.x + threadIdx.x;
  if (i >= SLOTS) return;
  int t = i>>1, k = i&1;
  int e = idxp[t*2+k];
  int slot = offs[e] + posp[t*2+k];
  tok_of[slot] = t;
  w_of[slot]   = wvp[t*2+k];
  slot_of[t*2+k] = slot;
}

// ---- gather x rows into per-expert-contiguous bf16 ----
__global__ __launch_bounds__(256) void gather_kernel(
    const float* __restrict__ x, const int* __restrict__ tok_of,
    unsigned short* __restrict__ Xg)
{
  int slot = blockIdx.x;
  int t = tok_of[slot];
  const float4* src = (const float4*)(x + (size_t)t*H_DIM);
  float4 v = src[threadIdx.x];
  ushort4 o;
  o.x=f2bf(v.x); o.y=f2bf(v.y); o.z=f2bf(v.z); o.w=f2bf(v.w);
  ((ushort4*)(Xg + (size_t)slot*H_DIM))[threadIdx.x] = o;
}

// ---- transpose + convert: in [e][R][C] fp32 -> out [e][C][R] bf16 ----
// 64x64 tile, float4 reads, ushort8 (16B/lane) transposed writes.
__global__ __launch_bounds__(256) void transconv_kernel(
    const float* __restrict__ in, unsigned short* __restrict__ out, int R, int C)
{
  __shared__ float tile[64][65];
  int e = blockIdx.z;
  const float* inp = in + (size_t)e*R*C;
  unsigned short* op = out + (size_t)e*R*C;
  int c0 = blockIdx.x*64, r0 = blockIdx.y*64;
  int tx = threadIdx.x & 15, ty = threadIdx.x >> 4;   // 16x16
  #pragma unroll
  for (int i=0;i<4;i++){
    int r = i*16 + ty;
    float4 v = *(const float4*)(inp + (size_t)(r0+r)*C + c0 + tx*4);
    tile[r][tx*4+0]=v.x; tile[r][tx*4+1]=v.y; tile[r][tx*4+2]=v.z; tile[r][tx*4+3]=v.w;
  }
  __syncthreads();
  int wx = threadIdx.x & 7;       // R-segment (8 rows of output)
  int wcl = threadIdx.x >> 3;     // 0..31
  #pragma unroll
  for (int i=0;i<2;i++){
    int c = i*32 + wcl;
    u16x8 o;
    #pragma unroll
    for (int j=0;j<8;j++) o[j] = f2bf(tile[wx*8+j][c]);
    *(u16x8*)(op + (size_t)(c0+c)*R + r0 + wx*8) = o;
  }
}

// ---- grouped GEMM: depth-2 counted-vmcnt pipeline (T3+T4 minimum form) ----
// Out[row][N] = epi(A[row][K] @ Bt[e][N][K]^T + bias[e][N])
// MODE 0: gelu epilogue (GEMM1). MODE 1: scale-by-gate-weight epilogue (GEMM2).
// 1D grid: blockIdx.x = tile*NCB + col  (NCB%8==0 -> B-panel pinned to XCD col%8)
template<int MODE>
__global__ __launch_bounds__(256) void gemm_kernel(
    const unsigned short* __restrict__ A,
    const unsigned short* __restrict__ Bt,
    const float* __restrict__ bias,
    unsigned short* __restrict__ Out,
    const int* __restrict__ tiles, const int* __restrict__ ntiles,
    const int* __restrict__ cnt, const int* __restrict__ offs,
    const float* __restrict__ w_of,
    int N, int K, int ncb_shift)
{
  int tile_id = blockIdx.x >> ncb_shift;
  if (tile_id >= *ntiles) return;
  int col0 = (blockIdx.x & ((1<<ncb_shift)-1)) << 7;
  int packed = tiles[tile_id];
  int e = packed>>16, mt = packed & 0xffff;
  int row0 = offs[e] + mt*BM;
  int nvalid = cnt[e] - mt*BM; if (nvalid > BM) nvalid = BM;
  const unsigned short* Be = Bt + (size_t)e*N*K;

  // double-buffered linear LDS: [128 rows][32 k] bf16 per buffer (16 KB x2 x2)
  __shared__ unsigned short As[2][128*32];
  __shared__ unsigned short Bs[2][128*32];

  int t = threadIdx.x;
  int wid = t>>6, lane = t&63;
  int wr = (wid>>1)*64, wc = (wid&1)*64;
  int fr = lane&15, fq = lane>>4;
  int cb = wid*64;                 // wave-uniform chunk base (16B chunks)

  // per-lane staging addresses (chunk c: row=c>>2, kq=c&3 -> LDS byte c*16)
  int c0c = cb + lane;
  int c1c = cb + 256 + lane;
  const unsigned short* gA0 = A  + (size_t)(row0 + (c0c>>2))*K + (c0c&3)*8;
  const unsigned short* gA1 = A  + (size_t)(row0 + (c1c>>2))*K + (c1c&3)*8;
  const unsigned short* gB0 = Be + (size_t)(col0 + (c0c>>2))*K + (c0c&3)*8;
  const unsigned short* gB1 = Be + (size_t)(col0 + (c1c>>2))*K + (c1c&3)*8;
  int ldsOff0 = cb*16, ldsOff1 = (cb+256)*16;

  auto stage = [&](int buf, int k0){
    __builtin_amdgcn_global_load_lds((global_cvoid*)(gA0 + k0),
        (lds_void*)((char*)&As[buf][0] + ldsOff0), 16, 0, 0);
    __builtin_amdgcn_global_load_lds((global_cvoid*)(gB0 + k0),
        (lds_void*)((char*)&Bs[buf][0] + ldsOff0), 16, 0, 0);
    __builtin_amdgcn_global_load_lds((global_cvoid*)(gA1 + k0),
        (lds_void*)((char*)&As[buf][0] + ldsOff1), 16, 0, 0);
    __builtin_amdgcn_global_load_lds((global_cvoid*)(gB1 + k0),
        (lds_void*)((char*)&Bs[buf][0] + ldsOff1), 16, 0, 0);
  };

  f32x4 acc[4][4];
  #pragma unroll
  for (int i=0;i<4;i++)
    #pragma unroll
    for (int j=0;j<4;j++) acc[i][j] = (f32x4){0.f,0.f,0.f,0.f};

  int NT = K >> 5;
  stage(0, 0);     // 4 vmem per wave
  stage(1, 32);    // 4 more: 8 outstanding
  int cur = 0;
  for (int kt=0; kt<NT; ++kt){
    // retire stage kt (oldest 4); keep stage kt+1 (and kt+2 later) in flight
    if (kt + 2 < NT) asm volatile("s_waitcnt vmcnt(4)" ::: "memory");
    else             asm volatile("s_waitcnt vmcnt(0)" ::: "memory");
    __builtin_amdgcn_s_barrier();   // all waves' stage-kt loads landed

    s16x8 af[4], bfr[4];
    #pragma unroll
    for (int i=0;i<4;i++){
      af[i]  = *(const s16x8*)&As[cur][(wr + i*16 + fr)*32 + fq*8];
      bfr[i] = *(const s16x8*)&Bs[cur][(wc + i*16 + fr)*32 + fq*8];
    }
    #pragma unroll
    for (int i=0;i<4;i++)
      #pragma unroll
      for (int j=0;j<4;j++)
        acc[i][j] = __builtin_amdgcn_mfma_f32_16x16x32_bf16(af[i], bfr[j], acc[i][j], 0,0,0);

    // ensure this wave's ds_reads retired and cannot sink past the barrier
    asm volatile("s_waitcnt lgkmcnt(0)" ::: "memory");
    __builtin_amdgcn_s_barrier();   // all waves done reading buf[cur]
    if (kt + 2 < NT) stage(cur, (kt+2)*32);  // overwrite freed buffer
    cur ^= 1;
  }

  // epilogue: C/D layout col=lane&15, row=(lane>>4)*4+reg (m89-verified)
  #pragma unroll
  for (int i=0;i<4;i++){
    #pragma unroll
    for (int r=0;r<4;r++){
      int lrow = wr + i*16 + fq*4 + r;
      if (lrow < nvalid){
        int grow = row0 + lrow;
        float scale = (MODE==1) ? w_of[grow] : 0.f;
        #pragma unroll
        for (int j=0;j<4;j++){
          int col = col0 + wc + j*16 + fr;
          float v = acc[i][j][r] + bias[(size_t)e*N + col];
          if (MODE==0) v = 0.5f*v*(1.f + erff(v*0.70710678118654752f));  // exact gelu
          else         v *= scale;
          Out[(size_t)grow*N + col] = f2bf(v);
        }
      }
    }
  }
}

// ---- combine: out[t] = y[slot0] + y[slot1] (gate weights already applied) ----
__global__ __launch_bounds__(256) void combine_kernel(
    const unsigned short* __restrict__ y, const int* __restrict__ slot_of,
    float* __restrict__ out)
{
  int tok = blockIdx.x;
  int s0 = slot_of[tok*2], s1 = slot_of[tok*2+1];
  const ushort4* y0 = (const ushort4*)(y + (size_t)s0*H_DIM);
  const ushort4* y1 = (const ushort4*)(y + (size_t)s1*H_DIM);
  float4* o = (float4*)(out + (size_t)tok*H_DIM);
  ushort4 a = y0[threadIdx.x], b = y1[threadIdx.x];
  float4 r;
  r.x = bf2f(a.x)+bf2f(b.x);
  r.y = bf2f(a.y)+bf2f(b.y);
  r.z = bf2f(a.z)+bf2f(b.z);
  r.w = bf2f(a.w)+bf2f(b.w);
  o[threadIdx.x] = r;
}

extern "C" void kernel_launch(void* const* d_in, const int* in_sizes, int n_in,
                              void* d_out, int out_size, void* d_ws, size_t ws_size,
                              hipStream_t stream) {
  const float* x  = (const float*)d_in[0];
  const float* Wg = (const float*)d_in[1];
  const float* bg = (const float*)d_in[2];
  const float* W1 = (const float*)d_in[3];
  const float* b1 = (const float*)d_in[4];
  const float* W2 = (const float*)d_in[5];
  const float* b2 = (const float*)d_in[6];
  float* out = (float*)d_out;
  char* ws = (char*)d_ws;

  int*   cnt     = (int*)  (ws + OFF_CNT);
  int*   offs    = (int*)  (ws + OFF_OFFS);
  int*   ntiles  = (int*)  (ws + OFF_NT);
  int*   tiles   = (int*)  (ws + OFF_TILES);
  int*   idxp    = (int*)  (ws + OFF_IDX);
  int*   posp    = (int*)  (ws + OFF_POS);
  float* wvp     = (float*)(ws + OFF_WV);
  int*   slot_of = (int*)  (ws + OFF_SLOT);
  int*   tok_of  = (int*)  (ws + OFF_TOK);
  float* w_of    = (float*)(ws + OFF_WOF);
  unsigned short* Xg  = (unsigned short*)(ws + OFF_XG);
  unsigned short* W1t = (unsigned short*)(ws + OFF_W1T);
  unsigned short* W2t = (unsigned short*)(ws + OFF_W2T);
  unsigned short* mid = (unsigned short*)(ws + OFF_MID);
  unsigned short* y   = (unsigned short*)(ws + OFF_Y);

  hipMemsetAsync(ws + OFF_CNT, 0, 32, stream);

  gate_kernel<<<T_TOK, 64, 0, stream>>>(x, Wg, bg, cnt, idxp, posp, wvp);
  plan_kernel<<<1, 1, 0, stream>>>(cnt, offs, tiles, ntiles);
  scatter_kernel<<<SLOTS/256, 256, 0, stream>>>(idxp, posp, wvp, offs, tok_of, w_of, slot_of);
  gather_kernel<<<SLOTS, 256, 0, stream>>>(x, tok_of, Xg);

  // W1 [E][H][FF] -> W1t [E][FF][H] ; W2 [E][FF][H] -> W2t [E][H][FF]
  transconv_kernel<<<dim3(FF_DIM/64, H_DIM/64, E_NUM), 256, 0, stream>>>(W1, W1t, H_DIM, FF_DIM);
  transconv_kernel<<<dim3(H_DIM/64, FF_DIM/64, E_NUM), 256, 0, stream>>>(W2, W2t, FF_DIM, H_DIM);

  // GEMM1: mid = gelu(Xg @ W1[e] + b1[e]), N=FF (32 col-blocks), K=H
  gemm_kernel<0><<<dim3(MAXTILES*32), 256, 0, stream>>>(
      Xg, W1t, b1, mid, tiles, ntiles, cnt, offs, nullptr, FF_DIM, H_DIM, 5);
  // GEMM2: y = (mid @ W2[e] + b2[e]) * gate_w, N=H (8 col-blocks), K=FF
  gemm_kernel<1><<<dim3(MAXTILES*8), 256, 0, stream>>>(
      mid, W2t, b2, y, tiles, ntiles, cnt, offs, w_of, H_DIM, FF_DIM, 3);

  combine_kernel<<<T_TOK, 256, 0, stream>>>(y, slot_of, out);
}